// Round 1
// baseline (1750.956 us; speedup 1.0000x reference)
//
#include <hip/hip_runtime.h>
#include <math.h>

// Problem constants
#define B_  16
#define IC_ 16
#define D_  16
#define H_  128
#define W_  128
#define OC_ 32
#define DP_ 14   // D' = D - 2
#define HP_ 126  // H' = H - 2
#define WP_ 126  // W' = W - 2

// ---------------------------------------------------------------------------
// Pre-kernel: transpose weight [OC][IC][3][3][3] -> wt[ic*27 + kd*9+kh*3+kw][OC]
// so that the 32 per-tap weights are contiguous (two s_load_dwordx16).
// ---------------------------------------------------------------------------
__global__ void transpose_w_kernel(const float* __restrict__ w,
                                   float* __restrict__ wt) {
    int i = blockIdx.x * 256 + threadIdx.x;
    if (i >= OC_ * IC_ * 27) return;
    int oc = i / (IC_ * 27);      // [oc][ic][kd][kh][kw] flat
    int r  = i % (IC_ * 27);      // ic*27 + kd*9 + kh*3 + kw
    wt[r * OC_ + oc] = w[i];
}

// ---------------------------------------------------------------------------
// Main kernel: one thread per output pixel (b, hp, wp).
// Thread keeps acc[32] (per-d' conv) and mn[32] (running min over d') in VGPRs.
// Weights are uniform across the block -> compiler emits scalar loads (SGPRs),
// so the inner loop is pure v_fmac_f32 (src0 = SGPR weight, src1 = x value).
// Block = 256 threads = 128 wp-lanes x 2 hp rows; grid = (63 hp-pairs, 16 b).
// ---------------------------------------------------------------------------
__launch_bounds__(256, 2)
__global__ void conv_min_softmax_kernel(const float* __restrict__ x,
                                        const float* __restrict__ wt,
                                        const float* __restrict__ bias,
                                        float* __restrict__ out) {
    const int tid  = threadIdx.x;
    const int wp   = tid & 127;
    const int hsub = tid >> 7;                 // 0..1
    const int hp   = blockIdx.x * 2 + hsub;    // 0..125
    const int b    = blockIdx.y;

    if (wp >= WP_) return;                     // lanes 126,127 idle; no barriers used

    const float* xb = x + (size_t)b * IC_ * D_ * H_ * W_;

    float mn[OC_];
#pragma unroll
    for (int oc = 0; oc < OC_; ++oc) mn[oc] = INFINITY;

    for (int dp = 0; dp < DP_; ++dp) {
        float acc[OC_];
#pragma unroll
        for (int oc = 0; oc < OC_; ++oc) acc[oc] = 0.0f;

        for (int ic = 0; ic < IC_; ++ic) {
#pragma unroll
            for (int kd = 0; kd < 3; ++kd) {
                const float* xplane = xb + ((size_t)(ic * D_ + dp + kd) * H_) * W_;
#pragma unroll
                for (int kh = 0; kh < 3; ++kh) {
                    const float* xrow = xplane + (size_t)(hp + kh) * W_ + wp;
#pragma unroll
                    for (int kw = 0; kw < 3; ++kw) {
                        const float xv = xrow[kw];
                        const float* wrow = wt + (size_t)((ic * 27) + kd * 9 + kh * 3 + kw) * OC_;
#pragma unroll
                        for (int oc = 0; oc < OC_; ++oc) {
                            acc[oc] = fmaf(xv, wrow[oc], acc[oc]);
                        }
                    }
                }
            }
        }
#pragma unroll
        for (int oc = 0; oc < OC_; ++oc) mn[oc] = fminf(mn[oc], acc[oc]);
    }

    // bias + softmax over the 32 channels (all in registers)
    float mx = -INFINITY;
#pragma unroll
    for (int oc = 0; oc < OC_; ++oc) {
        mn[oc] += bias[oc];
        mx = fmaxf(mx, mn[oc]);
    }
    float sum = 0.0f;
#pragma unroll
    for (int oc = 0; oc < OC_; ++oc) {
        mn[oc] = __expf(mn[oc] - mx);
        sum += mn[oc];
    }
    const float inv = 1.0f / sum;

    const size_t plane = (size_t)HP_ * WP_;
    size_t obase = (size_t)b * OC_ * plane + (size_t)hp * WP_ + wp;
#pragma unroll
    for (int oc = 0; oc < OC_; ++oc) {
        out[obase + (size_t)oc * plane] = mn[oc] * inv;
    }
}

extern "C" void kernel_launch(void* const* d_in, const int* in_sizes, int n_in,
                              void* d_out, int out_size, void* d_ws, size_t ws_size,
                              hipStream_t stream) {
    const float* x    = (const float*)d_in[0];
    const float* w    = (const float*)d_in[1];
    const float* bias = (const float*)d_in[2];
    float* out        = (float*)d_out;
    float* wt         = (float*)d_ws;   // 13824 floats = 55 KB scratch

    // 1) transpose weights into scratch (d_ws is re-poisoned every call, so redo it)
    {
        int n = OC_ * IC_ * 27;
        transpose_w_kernel<<<(n + 255) / 256, 256, 0, stream>>>(w, wt);
    }

    // 2) fused conv -> min(depth) -> softmax(channels)
    {
        dim3 grid(HP_ / 2, B_);   // 63 x 16 = 1008 blocks
        conv_min_softmax_kernel<<<grid, 256, 0, stream>>>(x, wt, bias, out);
    }
}

// Round 2
// 538.420 us; speedup vs baseline: 3.2520x; 3.2520x over previous
//
#include <hip/hip_runtime.h>
#include <math.h>

// Problem constants
#define Bn  16
#define ICn 16
#define Dn  16
#define Hn  128
#define Wn  128
#define OCn 32
#define DPn 14
#define HPn 126
#define WPn 126

typedef _Float16 half_t;
typedef __attribute__((ext_vector_type(4)))  _Float16 half4;
typedef __attribute__((ext_vector_type(8)))  _Float16 half8;
typedef __attribute__((ext_vector_type(16))) float    float16v;

// Tile config: wg = 4 waves; each wave: 32 pixels (2 rows x 16 cols) x 32 oc.
#define TH 8            // output rows per wg (4 waves x 2 rows)
#define TW 16           // output cols per wg
#define SR 10           // staged rows  (TH + 2 halo)
#define SC 18           // staged cols  (TW + 2 halo)
#define ICP 20          // ic padded 16 -> 20 (40B col stride: 8B-aligned, ~2-way banks = free)
#define SLOT_BYTES (SR*SC*ICP*2)     // 7200 B per depth-plane slot
#define EP_PAD 33                    // epilogue transpose pad (33 dwords -> conflict-free)
#define ROW_B (SC*ICP*2)             // 720 B per staged row
#define COL_B (ICP*2)                // 40 B per staged col

// ---------------------------------------------------------------------------
// Pack weights into B-fragment order for mfma_f32_32x32x16_f16:
//   B-frag: lane l holds B[n = l&31][k = (l>>5)*8 + j], j=0..7  (n=oc, k=ic)
//   wB[tap][lane][j] f16, tap = kd*9 + kh*3 + kw
// ---------------------------------------------------------------------------
__global__ void pack_w_kernel(const float* __restrict__ w, half_t* __restrict__ wB) {
    int i = blockIdx.x * 256 + threadIdx.x;      // over 27*64*8 = 13824
    if (i >= 27 * 64 * 8) return;
    int tap = i >> 9;                            // /512
    int l   = (i >> 3) & 63;
    int j   = i & 7;
    int oc  = l & 31;
    int ic  = ((l >> 5) << 3) + j;
    wB[i] = (half_t)w[(oc * ICn + ic) * 27 + tap];
}

// ---------------------------------------------------------------------------
// Fused implicit-GEMM conv3d -> min(depth) -> softmax(channels), f16 MFMA.
// ---------------------------------------------------------------------------
__launch_bounds__(256, 2)
__global__ void conv_min_softmax_mfma(const float* __restrict__ x,
                                      const half_t* __restrict__ wB,
                                      const float* __restrict__ bias,
                                      float* __restrict__ out) {
    __shared__ __align__(16) char smem[3 * SLOT_BYTES + 4 * 32 * EP_PAD * 4];

    const int tid    = threadIdx.x;
    const int lane   = tid & 63;
    const int wv     = tid >> 6;                  // wave 0..3 -> rows 2wv..2wv+1
    const int wpbase = blockIdx.x * TW;
    const int hpbase = blockIdx.y * TH;
    const int b      = blockIdx.z;

    const float* xb = x + (size_t)b * ICn * Dn * Hn * Wn;

    // ---- preload all 27 tap B-fragments into VGPRs (coalesced dwordx4) ----
    half8 wf[27];
#pragma unroll
    for (int t = 0; t < 27; ++t)
        wf[t] = *(const half8*)(wB + ((size_t)t * 64 + lane) * 8);

    // ---- staging: one depth-plane (all 16 ic) into an LDS slot, f32->f16 ----
    auto stage = [&](int d, int slotByteOff) {
        char* sbase = smem + slotByteOff;
        for (int i = tid; i < SR * SC * 8; i += 256) {     // 1440 ic-pairs
            int icp = i / (SR * SC);                       // 0..7
            int rem = i % (SR * SC);
            int row = rem / SC, col = rem % SC;
            int gr = hpbase + row; if (gr > Hn - 1) gr = Hn - 1;   // clamp halo
            int gc = wpbase + col; if (gc > Wn - 1) gc = Wn - 1;
            const float* p = xb + ((size_t)(2 * icp) * Dn + d) * Hn * Wn
                                + (size_t)gr * Wn + gc;
            float v0 = p[0];
            float v1 = p[(size_t)Dn * Hn * Wn];            // next ic, same (d,h,w)
            union { half_t h[2]; unsigned u; } pk;
            pk.h[0] = (half_t)v0; pk.h[1] = (half_t)v1;    // RTE converts
            *(unsigned*)(sbase + rem * COL_B + 2 * icp * 2) = pk.u;
        }
    };

    // A-frag lane decode: m = lane&31 -> pixel (prow=m>>4, pcol=m&15); h = lane>>5
    const int m    = lane & 31;
    const int h    = lane >> 5;
    const int prow = m >> 4, pcol = m & 15;
    const int albase = (2 * wv + prow) * ROW_B + pcol * COL_B + 16 * h;

    // ---- prologue: stage planes 0,1,2 ----
    stage(0, 0); stage(1, SLOT_BYTES); stage(2, 2 * SLOT_BYTES);
    int s0 = 0, s1 = SLOT_BYTES, s2 = 2 * SLOT_BYTES;   // slots for planes dp, dp+1, dp+2
    __syncthreads();

    float16v mn;
#pragma unroll
    for (int r = 0; r < 16; ++r) mn[r] = INFINITY;

    for (int dp = 0; dp < DPn; ++dp) {
        float16v acc;
#pragma unroll
        for (int r = 0; r < 16; ++r) acc[r] = 0.0f;

        int sb[3] = { s0, s1, s2 };
#pragma unroll
        for (int kd = 0; kd < 3; ++kd) {
            const char* ab = smem + sb[kd] + albase;
#pragma unroll
            for (int kh = 0; kh < 3; ++kh) {
#pragma unroll
                for (int kw = 0; kw < 3; ++kw) {
                    const int off = kh * ROW_B + kw * COL_B;   // compile-time imm
                    half4 a0 = *(const half4*)(ab + off);
                    half4 a1 = *(const half4*)(ab + off + 8);
                    half8 a = __builtin_shufflevector(a0, a1, 0, 1, 2, 3, 4, 5, 6, 7);
                    acc = __builtin_amdgcn_mfma_f32_32x32x16_f16(a, wf[kd * 9 + kh * 3 + kw], acc, 0, 0, 0);
                }
            }
        }
#pragma unroll
        for (int r = 0; r < 16; ++r) mn[r] = fminf(mn[r], acc[r]);

        if (dp < DPn - 1) {
            __syncthreads();                       // all waves done reading slot s0
            if (dp + 3 < Dn) stage(dp + 3, s0);    // overwrite plane dp with dp+3
            __syncthreads();
            int t = s0; s0 = s1; s1 = s2; s2 = t;  // rotate ring
        }
    }

    // ---- epilogue: bias + softmax over oc (32-lane shfl), transpose via LDS ----
    const int oc = m;                    // C/D: col(n=oc) = lane&31
    const float bv = bias[oc];
    float* ep = (float*)(smem + 3 * SLOT_BYTES);

#pragma unroll
    for (int reg = 0; reg < 16; ++reg) {
        float v = mn[reg] + bv;
        float mx = v;
#pragma unroll
        for (int off = 1; off < 32; off <<= 1)
            mx = fmaxf(mx, __shfl_xor(mx, off, 64));
        float e = __expf(v - mx);
        float s = e;
#pragma unroll
        for (int off = 1; off < 32; off <<= 1)
            s += __shfl_xor(s, off, 64);
        float pr = e / s;
        int mc = (reg & 3) + ((reg >> 2) << 3) + 4 * h;    // C/D row (pixel index)
        ep[(wv * 32 + mc) * EP_PAD + oc] = pr;
    }
    __syncthreads();

    // coalesced stores: [oc][row][col] runs of 16 contiguous floats
    for (int i = tid; i < 32 * TH * TW; i += 256) {        // 4096
        int oc2  = i >> 7;
        int rrow = (i >> 4) & 7;
        int col  = i & 15;
        int wvs = rrow >> 1, pr2 = rrow & 1;
        int mc  = pr2 * 16 + col;
        float val = ep[(wvs * 32 + mc) * EP_PAD + oc2];
        int hp = hpbase + rrow, wp = wpbase + col;
        if (hp < HPn && wp < WPn)
            out[((b * OCn + oc2) * HPn + hp) * WPn + wp] = val;
    }
}

extern "C" void kernel_launch(void* const* d_in, const int* in_sizes, int n_in,
                              void* d_out, int out_size, void* d_ws, size_t ws_size,
                              hipStream_t stream) {
    const float* x    = (const float*)d_in[0];
    const float* w    = (const float*)d_in[1];
    const float* bias = (const float*)d_in[2];
    float* out        = (float*)d_out;
    half_t* wB        = (half_t*)d_ws;           // 13824 f16 = 27.6 KB scratch

    {
        int n = 27 * 64 * 8;
        pack_w_kernel<<<(n + 255) / 256, 256, 0, stream>>>(w, wB);
    }
    {
        dim3 grid((WPn + TW - 1) / TW,           // 8 col-blocks
                  (HPn + TH - 1) / TH,           // 16 row-blocks
                  Bn);                           // 16 batches
        conv_min_softmax_mfma<<<grid, 256, 0, stream>>>(x, wB, bias, out);
    }
}